// Round 2
// baseline (1796.157 us; speedup 1.0000x reference)
//
#include <hip/hip_runtime.h>

// Forward bilinear warp (splat) via LDS privatization, channel-grouped.
//   im0:  [B, C, H, W] fp32
//   flow: [B, H, W, 2] fp32 (dx, dy)
//   out:  [B, C, H, W] fp32
//
// Kernel 1: each block owns a TS x TS spatial tile for CG=4 channels of one
// batch. Flow math (floor, weights, window check) is done ONCE per pixel and
// reused for the 4 channels -> 4x fewer loop iterations than 1-channel blocks
// and 8B flow load amortized. 1024 threads (16 waves/CU at 1 block/CU from
// the 147 KB LDS window) doubles latency hiding vs the 512-thread version.
// Splats land in acc[CG][WIN][WIN] via ds_add_f32. Flush: exclusive interior
// -> plain store; ring -> global atomicAdd (skip zeros). Pixels whose corners
// fall outside the window are replayed by Kernel 2 (global atomics), which
// runs after Kernel 1 on the stream, so ordering vs plain stores is safe.

#define TS   80
#define R    8
#define WIN  96             // TS + 2R
#define CG   4              // channels per block
#define NCG  8              // C / CG
#define NT1  1024
#define TILES_X 11          // ceil(854/80)
#define TILES_Y 6           // 480/80
#define NTILES (TILES_X * TILES_Y)

__global__ __launch_bounds__(NT1)
void fw_warp_tiled(const float* __restrict__ im0,
                   const float* __restrict__ flow,
                   float* __restrict__ out) {
    const int C = 32, H = 480, W = 854;
    const int HW = H * W;
    __shared__ float acc[CG * WIN * WIN];   // 147,456 B -> 1 block/CU

    const int cg = blockIdx.x;              // channel group 0..7
    const int tI = blockIdx.y;              // tile 0..65
    const int b  = blockIdx.z;
    const int tx0 = (tI % TILES_X) * TS;
    const int ty0 = (tI / TILES_X) * TS;
    const int tid = threadIdx.x;

    for (int i = tid; i < CG * WIN * WIN; i += NT1) acc[i] = 0.0f;
    __syncthreads();

    const float*  imp = im0 + (size_t)(b * C + cg * CG) * HW;
    const float2* flp = (const float2*)flow + (size_t)b * HW;

    for (int i = tid; i < TS * TS; i += NT1) {
        int py = i / TS, px = i - py * TS;
        int y = ty0 + py, x = tx0 + px;
        if (x >= W) continue;               // partial right-edge tile (y always < H)
        float2 f = flp[y * W + x];
        float xf = (float)x + f.x;
        float yf = (float)y + f.y;
        float x0f = floorf(xf), y0f = floorf(yf);
        int x0 = (int)x0f, y0 = (int)y0f;
        // both corners (x0, x0+1) must be inside the LDS window
        if (x0 < tx0 - R || x0 > tx0 + TS + R - 2 ||
            y0 < ty0 - R || y0 > ty0 + TS + R - 2) continue;  // kernel 2
        float wx1 = xf - x0f, wx0 = 1.0f - wx1;
        float wy1 = yf - y0f, wy0 = 1.0f - wy1;
        float w00 = wx0 * wy0, w10 = wx1 * wy0;
        float w01 = wx0 * wy1, w11 = wx1 * wy1;

        // 4 independent channel loads off one base -> issued together (MLP)
        const float* ip = imp + (size_t)y * W + x;
        float v0 = ip[0];
        float v1 = ip[HW];
        float v2 = ip[2 * HW];
        float v3 = ip[3 * HW];

        int lx = x0 - (tx0 - R);
        int ly = y0 - (ty0 - R);
        float* p = &acc[ly * WIN + lx];
        atomicAdd(p,           v0 * w00);
        atomicAdd(p + 1,       v0 * w10);
        atomicAdd(p + WIN,     v0 * w01);
        atomicAdd(p + WIN + 1, v0 * w11);
        p += WIN * WIN;
        atomicAdd(p,           v1 * w00);
        atomicAdd(p + 1,       v1 * w10);
        atomicAdd(p + WIN,     v1 * w01);
        atomicAdd(p + WIN + 1, v1 * w11);
        p += WIN * WIN;
        atomicAdd(p,           v2 * w00);
        atomicAdd(p + 1,       v2 * w10);
        atomicAdd(p + WIN,     v2 * w01);
        atomicAdd(p + WIN + 1, v2 * w11);
        p += WIN * WIN;
        atomicAdd(p,           v3 * w00);
        atomicAdd(p + 1,       v3 * w10);
        atomicAdd(p + WIN,     v3 * w01);
        atomicAdd(p + WIN + 1, v3 * w11);
    }
    __syncthreads();

    float* outp = out + (size_t)(b * C + cg * CG) * HW;
    for (int i = tid; i < WIN * WIN; i += NT1) {
        int wy = i / WIN, wx = i - wy * WIN;
        int gy = ty0 - R + wy;
        int gx = tx0 - R + wx;
        if ((unsigned)gy < (unsigned)H && (unsigned)gx < (unsigned)W) {
            // exclusive interior: >= R px inside the tile border -> no other
            // block's window reaches it; kernel 2 adds after us (ordered).
            bool interior = (wy >= 2 * R) && (wy < TS) && (wx >= 2 * R) && (wx < TS);
            size_t o = (size_t)gy * W + gx;
            #pragma unroll
            for (int c = 0; c < CG; ++c) {
                float v = acc[c * WIN * WIN + i];
                if (interior)          outp[(size_t)c * HW + o] = v;
                else if (v != 0.0f)    atomicAdd(&outp[(size_t)c * HW + o], v);
            }
        }
    }
}

// Kernel 2: replay pixels whose splat window check failed, with global atomics.
// Must use the SAME TS/R/window predicate as kernel 1.
__global__ __launch_bounds__(256)
void fw_warp_far(const float* __restrict__ im0,
                 const float* __restrict__ flow,
                 float* __restrict__ out) {
    const int C = 32, H = 480, W = 854;
    int tid = blockIdx.x * blockDim.x + threadIdx.x;
    const int total = 4 * H * W;
    if (tid >= total) return;
    int x = tid % W;
    int t = tid / W;
    int y = t % H;
    int b = t / H;

    float2 f = ((const float2*)flow)[tid];
    float xf = (float)x + f.x;
    float yf = (float)y + f.y;
    float x0f = floorf(xf), y0f = floorf(yf);
    int x0 = (int)x0f, y0 = (int)y0f;
    int tx0 = (x / TS) * TS;
    int ty0 = (y / TS) * TS;
    bool inwin = !(x0 < tx0 - R || x0 > tx0 + TS + R - 2 ||
                   y0 < ty0 - R || y0 > ty0 + TS + R - 2);
    if (inwin) return;   // kernel 1 handled it

    float wx1 = xf - x0f, wx0 = 1.0f - wx1;
    float wy1 = yf - y0f, wy0 = 1.0f - wy1;
    bool xv0 = (unsigned)x0       < (unsigned)W;
    bool xv1 = (unsigned)(x0 + 1) < (unsigned)W;
    bool yv0 = (unsigned)y0       < (unsigned)H;
    bool yv1 = (unsigned)(y0 + 1) < (unsigned)H;

    for (int c = 0; c < C; ++c) {
        float v = im0[(((size_t)(b * C + c)) * H + y) * W + x];
        float* op = out + ((size_t)(b * C + c) * H) * W;
        if (yv0 && xv0) atomicAdd(&op[(size_t)y0 * W + x0],           v * wx0 * wy0);
        if (yv0 && xv1) atomicAdd(&op[(size_t)y0 * W + x0 + 1],       v * wx1 * wy0);
        if (yv1 && xv0) atomicAdd(&op[(size_t)(y0 + 1) * W + x0],     v * wx0 * wy1);
        if (yv1 && xv1) atomicAdd(&op[(size_t)(y0 + 1) * W + x0 + 1], v * wx1 * wy1);
    }
}

extern "C" void kernel_launch(void* const* d_in, const int* in_sizes, int n_in,
                              void* d_out, int out_size, void* d_ws, size_t ws_size,
                              hipStream_t stream) {
    const float* im0  = (const float*)d_in[0];
    const float* flow = (const float*)d_in[1];
    float* out = (float*)d_out;

    const int B = 4, C = 32, H = 480, W = 854;

    hipMemsetAsync(d_out, 0, (size_t)out_size * sizeof(float), stream);

    dim3 grid1(NCG, NTILES, B);
    fw_warp_tiled<<<grid1, NT1, 0, stream>>>(im0, flow, out);

    const int totalPix = B * H * W;
    fw_warp_far<<<(totalPix + 255) / 256, 256, 0, stream>>>(im0, flow, out);
}

// Round 3
// 1565.533 us; speedup vs baseline: 1.1473x; 1.1473x over previous
//
#include <hip/hip_runtime.h>

// Forward bilinear warp (splat) via LDS privatization, channel-grouped,
// with ATOMIC-FREE flush: core -> direct store, halo -> private buffer,
// second gather pass sums overlapping halos. Kernel "far" replays outliers.
//
//   im0:  [B, C, H, W] fp32
//   flow: [B, H, W, 2] fp32 (dx, dy)
//   out:  [B, C, H, W] fp32

#define TS   80
#define R    8
#define WIN  96             // TS + 2R
#define CG   4              // channels per block
#define NCG  8              // C / CG
#define NT1  1024
#define TILES_X 11          // ceil(854/80)
#define TILES_Y 6           // 480/80
#define NTILES (TILES_X * TILES_Y)
#define HALO_CELLS 2816     // WIN*WIN - TS*TS = top/bot R*WIN*2 + l/r TS*R*2
#define B_  4
#define C_  32
#define H_  480
#define W_  854

// halo strip layout: [0,768): top R x WIN ; [768,1536): bottom R x WIN ;
// [1536,2176): left TS x R ; [2176,2816): right TS x R
__device__ __forceinline__ int halo_cell(int wy, int wx) {
    if (wy < R)       return wy * WIN + wx;
    if (wy >= TS + R) return R * WIN + (wy - (TS + R)) * WIN + wx;
    if (wx < R)       return 2 * R * WIN + (wy - R) * R + wx;
    return 2 * R * WIN + TS * R + (wy - R) * R + (wx - (TS + R));
}

template <bool USE_BUF>
__global__ __launch_bounds__(NT1)
void fw_warp_tiled(const float* __restrict__ im0,
                   const float* __restrict__ flow,
                   float* __restrict__ out,
                   float* __restrict__ buf) {
    const int C = C_, H = H_, W = W_;
    const int HW = H * W;
    __shared__ float acc[CG * WIN * WIN];   // 147,456 B -> 1 block/CU

    const int cg = blockIdx.x;              // channel group 0..7
    const int tI = blockIdx.y;              // tile 0..65
    const int b  = blockIdx.z;
    const int tx0 = (tI % TILES_X) * TS;
    const int ty0 = (tI / TILES_X) * TS;
    const int tid = threadIdx.x;

    for (int i = tid; i < CG * WIN * WIN; i += NT1) acc[i] = 0.0f;
    __syncthreads();

    const float*  imp = im0 + (size_t)(b * C + cg * CG) * HW;
    const float2* flp = (const float2*)flow + (size_t)b * HW;

    for (int i = tid; i < TS * TS; i += NT1) {
        int py = i / TS, px = i - py * TS;
        int y = ty0 + py, x = tx0 + px;
        if (x >= W) continue;               // partial right-edge tile
        float2 f = flp[y * W + x];
        float xf = (float)x + f.x;
        float yf = (float)y + f.y;
        float x0f = floorf(xf), y0f = floorf(yf);
        int x0 = (int)x0f, y0 = (int)y0f;
        // both corners (x0, x0+1) must be inside the LDS window
        if (x0 < tx0 - R || x0 > tx0 + TS + R - 2 ||
            y0 < ty0 - R || y0 > ty0 + TS + R - 2) continue;  // far kernel
        float wx1 = xf - x0f, wx0 = 1.0f - wx1;
        float wy1 = yf - y0f, wy0 = 1.0f - wy1;
        float w00 = wx0 * wy0, w10 = wx1 * wy0;
        float w01 = wx0 * wy1, w11 = wx1 * wy1;

        const float* ip = imp + (size_t)y * W + x;
        float v0 = ip[0];
        float v1 = ip[HW];
        float v2 = ip[2 * HW];
        float v3 = ip[3 * HW];

        int lx = x0 - (tx0 - R);
        int ly = y0 - (ty0 - R);
        float* p = &acc[ly * WIN + lx];
        atomicAdd(p,           v0 * w00);
        atomicAdd(p + 1,       v0 * w10);
        atomicAdd(p + WIN,     v0 * w01);
        atomicAdd(p + WIN + 1, v0 * w11);
        p += WIN * WIN;
        atomicAdd(p,           v1 * w00);
        atomicAdd(p + 1,       v1 * w10);
        atomicAdd(p + WIN,     v1 * w01);
        atomicAdd(p + WIN + 1, v1 * w11);
        p += WIN * WIN;
        atomicAdd(p,           v2 * w00);
        atomicAdd(p + 1,       v2 * w10);
        atomicAdd(p + WIN,     v2 * w01);
        atomicAdd(p + WIN + 1, v2 * w11);
        p += WIN * WIN;
        atomicAdd(p,           v3 * w00);
        atomicAdd(p + 1,       v3 * w10);
        atomicAdd(p + WIN,     v3 * w01);
        atomicAdd(p + WIN + 1, v3 * w11);
    }
    __syncthreads();

    float* outp = out + (size_t)(b * C + cg * CG) * HW;

    if (USE_BUF) {
        // core: every tile pixel written exactly once by this block (no memset,
        // no atomics). Ring/halo contributions arrive later via gather+far.
        for (int i = tid; i < TS * TS; i += NT1) {
            int py = i / TS, px = i - py * TS;
            int gx = tx0 + px;
            if (gx >= W_) continue;
            size_t o = (size_t)(ty0 + py) * W_ + gx;
            #pragma unroll
            for (int c = 0; c < CG; ++c)
                outp[(size_t)c * HW + o] = acc[(c * WIN + (R + py)) * WIN + (R + px)];
        }
        // halo frame -> private buffer (plain stores, dense, incl. zeros)
        float* bufp = buf + ((size_t)(b * C + cg * CG) * NTILES + tI) * HALO_CELLS;
        for (int i = tid; i < HALO_CELLS; i += NT1) {
            int wy, wx;
            if (i < R * WIN)            { wy = i / WIN;                 wx = i % WIN; }
            else if (i < 2 * R * WIN)   { int j = i - R * WIN;          wy = TS + R + j / WIN; wx = j % WIN; }
            else if (i < 2 * R * WIN + TS * R) { int j = i - 2 * R * WIN; wy = R + j / R; wx = j % R; }
            else                        { int j = i - 2 * R * WIN - TS * R; wy = R + j / R; wx = TS + R + j % R; }
            #pragma unroll
            for (int c = 0; c < CG; ++c)
                bufp[(size_t)c * NTILES * HALO_CELLS + i] = acc[(c * WIN + wy) * WIN + wx];
        }
    } else {
        // fallback (ws too small): original atomic ring flush; out pre-zeroed.
        for (int i = tid; i < WIN * WIN; i += NT1) {
            int wy = i / WIN, wx = i - wy * WIN;
            int gy = ty0 - R + wy;
            int gx = tx0 - R + wx;
            if ((unsigned)gy < (unsigned)H_ && (unsigned)gx < (unsigned)W_) {
                bool interior = (wy >= 2 * R) && (wy < TS) && (wx >= 2 * R) && (wx < TS);
                size_t o = (size_t)gy * W_ + gx;
                #pragma unroll
                for (int c = 0; c < CG; ++c) {
                    float v = acc[c * WIN * WIN + i];
                    if (interior)          outp[(size_t)c * HW + o] = v;
                    else if (v != 0.0f)    atomicAdd(&outp[(size_t)c * HW + o], v);
                }
            }
        }
    }
}

// Gather pass: each ring pixel sums the <=3 neighbor-tile halo cells that
// cover it. One owner thread per (b,y,x), all C channels -> no atomics.
__global__ __launch_bounds__(256)
void fw_warp_gather(const float* __restrict__ buf, float* __restrict__ out) {
    int tid = blockIdx.x * 256 + threadIdx.x;
    const int total = B_ * H_ * W_;
    if (tid >= total) return;
    int x = tid % W_;
    int t = tid / W_;
    int y = t % H_;
    int b = t / H_;
    int tx = x / TS, ty = y / TS;
    int px = x - tx * TS, py = y - ty * TS;
    bool rl = px < R, rr = px >= TS - R;
    bool rt = py < R, rb = py >= TS - R;
    if (!(rl | rr | rt | rb)) return;

    int dx = rl ? -1 : (rr ? 1 : 0);
    int dy = rt ? -1 : (rb ? 1 : 0);

    int t_h = -1, c_h = 0, t_v = -1, c_v = 0, t_d = -1, c_d = 0;
    if (dx) {
        int ntx = tx + dx;
        if ((unsigned)ntx < TILES_X) {
            t_h = ty * TILES_X + ntx;
            c_h = halo_cell(y - (ty * TS - R), x - (ntx * TS - R));
        }
    }
    if (dy) {
        int nty = ty + dy;
        if ((unsigned)nty < TILES_Y) {
            t_v = nty * TILES_X + tx;
            c_v = halo_cell(y - (nty * TS - R), x - (tx * TS - R));
        }
    }
    if (dx && dy) {
        int ntx = tx + dx, nty = ty + dy;
        if ((unsigned)ntx < TILES_X && (unsigned)nty < TILES_Y) {
            t_d = nty * TILES_X + ntx;
            c_d = halo_cell(y - (nty * TS - R), x - (ntx * TS - R));
        }
    }
    if ((t_h | t_v | t_d) < 0 && t_h < 0 && t_v < 0 && t_d < 0) return;

    const size_t HW = (size_t)H_ * W_;
    size_t o = (size_t)y * W_ + x;
    for (int c = 0; c < C_; ++c) {
        size_t cb = (size_t)(b * C_ + c);
        float s = out[cb * HW + o];
        if (t_h >= 0) s += buf[(cb * NTILES + t_h) * HALO_CELLS + c_h];
        if (t_v >= 0) s += buf[(cb * NTILES + t_v) * HALO_CELLS + c_v];
        if (t_d >= 0) s += buf[(cb * NTILES + t_d) * HALO_CELLS + c_d];
        out[cb * HW + o] = s;
    }
}

// Far kernel: replay pixels whose splat window check failed, global atomics.
// Must use the SAME TS/R/window predicate as the tiled kernel. Runs last.
__global__ __launch_bounds__(256)
void fw_warp_far(const float* __restrict__ im0,
                 const float* __restrict__ flow,
                 float* __restrict__ out) {
    const int C = C_, H = H_, W = W_;
    int tid = blockIdx.x * blockDim.x + threadIdx.x;
    const int total = B_ * H * W;
    if (tid >= total) return;
    int x = tid % W;
    int t = tid / W;
    int y = t % H;
    int b = t / H;

    float2 f = ((const float2*)flow)[tid];
    float xf = (float)x + f.x;
    float yf = (float)y + f.y;
    float x0f = floorf(xf), y0f = floorf(yf);
    int x0 = (int)x0f, y0 = (int)y0f;
    int tx0 = (x / TS) * TS;
    int ty0 = (y / TS) * TS;
    bool inwin = !(x0 < tx0 - R || x0 > tx0 + TS + R - 2 ||
                   y0 < ty0 - R || y0 > ty0 + TS + R - 2);
    if (inwin) return;   // tiled kernel handled it

    float wx1 = xf - x0f, wx0 = 1.0f - wx1;
    float wy1 = yf - y0f, wy0 = 1.0f - wy1;
    bool xv0 = (unsigned)x0       < (unsigned)W;
    bool xv1 = (unsigned)(x0 + 1) < (unsigned)W;
    bool yv0 = (unsigned)y0       < (unsigned)H;
    bool yv1 = (unsigned)(y0 + 1) < (unsigned)H;

    for (int c = 0; c < C; ++c) {
        float v = im0[(((size_t)(b * C + c)) * H + y) * W + x];
        float* op = out + ((size_t)(b * C + c) * H) * W;
        if (yv0 && xv0) atomicAdd(&op[(size_t)y0 * W + x0],           v * wx0 * wy0);
        if (yv0 && xv1) atomicAdd(&op[(size_t)y0 * W + x0 + 1],       v * wx1 * wy0);
        if (yv1 && xv0) atomicAdd(&op[(size_t)(y0 + 1) * W + x0],     v * wx0 * wy1);
        if (yv1 && xv1) atomicAdd(&op[(size_t)(y0 + 1) * W + x0 + 1], v * wx1 * wy1);
    }
}

extern "C" void kernel_launch(void* const* d_in, const int* in_sizes, int n_in,
                              void* d_out, int out_size, void* d_ws, size_t ws_size,
                              hipStream_t stream) {
    const float* im0  = (const float*)d_in[0];
    const float* flow = (const float*)d_in[1];
    float* out = (float*)d_out;

    const size_t need = (size_t)B_ * C_ * NTILES * HALO_CELLS * sizeof(float); // 95.2 MB
    const int totalPix = B_ * H_ * W_;
    dim3 grid1(NCG, NTILES, B_);

    if (d_ws != nullptr && ws_size >= need) {
        // atomic-free path: cores cover every out pixel (no memset needed)
        fw_warp_tiled<true><<<grid1, NT1, 0, stream>>>(im0, flow, out, (float*)d_ws);
        fw_warp_gather<<<(totalPix + 255) / 256, 256, 0, stream>>>((const float*)d_ws, out);
    } else {
        hipMemsetAsync(d_out, 0, (size_t)out_size * sizeof(float), stream);
        fw_warp_tiled<false><<<grid1, NT1, 0, stream>>>(im0, flow, out, nullptr);
    }
    fw_warp_far<<<(totalPix + 255) / 256, 256, 0, stream>>>(im0, flow, out);
}